// Round 3
// baseline (289.441 us; speedup 1.0000x reference)
//
#include <hip/hip_runtime.h>
#include <math.h>

// Problem constants (from reference): T=512, E=64, H=2*E=128.
#define TT 512
#define EE 64
#define HH 128
#define UNROLL 8

typedef float v4f __attribute__((ext_vector_type(4)));   // native vec: ok for nontemporal builtins

// Kernel 1: rows[d][h] = (gelu_exact(pos[d] @ W1 + b1) @ W2 + b2)[h]
// One block per distance d (512 blocks), 128 threads (one per output column h).
__global__ void rows_kernel(const float* __restrict__ pos,
                            const float* __restrict__ W1,
                            const float* __restrict__ b1,
                            const float* __restrict__ W2,
                            const float* __restrict__ b2,
                            float* __restrict__ rows) {
    const int d = blockIdx.x;
    const int t = threadIdx.x;   // 0..127

    __shared__ float p[EE];   // pos_table row d
    __shared__ float h[HH];   // hidden activations

    if (t < EE) p[t] = pos[d * EE + t];
    __syncthreads();

    // h[t] = gelu(pos[d] . W1[:,t] + b1[t]), exact gelu (erf form)
    float acc = b1[t];
#pragma unroll
    for (int e = 0; e < EE; ++e) acc += p[e] * W1[e * HH + t];
    h[t] = 0.5f * acc * (1.0f + erff(acc * 0.7071067811865475f));
    __syncthreads();

    // rows[d][t] = h . W2[:,t] + b2[t]
    float acc2 = b2[t];
#pragma unroll
    for (int k = 0; k < HH; ++k) acc2 += h[k] * W2[k * HH + t];
    rows[d * HH + t] = acc2;
}

// Kernel 2: out[b][i][j][:] = rows[max(i-j,0)][:]
// Grid-stride, UNROLL independent load/store pairs per thread for MLP.
// Per store instruction the wave is contiguous (64 lanes x 16 B = 1 KB).
// Output stores are non-temporal: the 268 MB write stream must not evict
// the 256 KB rows table from L2.
__global__ __launch_bounds__(256)
void scatter_kernel(const v4f* __restrict__ rows4,
                    v4f* __restrict__ out4, int total4) {
    const int S    = blockDim.x * gridDim.x;           // stride between unroll slots
    const int idx0 = blockIdx.x * blockDim.x + threadIdx.x;

    v4f v[UNROLL];
    int id[UNROLL];

#pragma unroll
    for (int k = 0; k < UNROLL; ++k) {
        const int idx = idx0 + k * S;
        const int q = idx & 31;                 // float4 within row (HH/4=32)
        const int r = idx >> 5;                 // flat (b,i,j)
        const int j = r & (TT - 1);
        const int i = (r >> 9) & (TT - 1);
        const int d = (i >= j) ? (i - j) : 0;   // tril(i-j)
        id[k] = idx;
        v[k]  = rows4[d * (HH / 4) + q];        // L2-hot (256 KB table)
    }
#pragma unroll
    for (int k = 0; k < UNROLL; ++k) {
        if (id[k] < total4)
            __builtin_nontemporal_store(v[k], &out4[id[k]]);
    }
}

extern "C" void kernel_launch(void* const* d_in, const int* in_sizes, int n_in,
                              void* d_out, int out_size, void* d_ws, size_t ws_size,
                              hipStream_t stream) {
    // setup_inputs order: b(int scalar), pos_table, W1, b1, W2, b2 — all fp32
    const float* pos = (const float*)d_in[1];
    const float* W1  = (const float*)d_in[2];
    const float* b1  = (const float*)d_in[3];
    const float* W2  = (const float*)d_in[4];
    const float* b2  = (const float*)d_in[5];
    float* out  = (float*)d_out;
    float* rows = (float*)d_ws;              // TT*HH*4 = 256 KB scratch

    rows_kernel<<<TT, HH, 0, stream>>>(pos, W1, b1, W2, b2, rows);

    const int total4 = out_size / 4;         // out_size = b*TT*TT*HH
    const int block  = 256;
    const int grid   = (total4 + block * UNROLL - 1) / (block * UNROLL);
    scatter_kernel<<<grid, block, 0, stream>>>((const v4f*)rows,
                                               (v4f*)out, total4);
}

// Round 4
// 269.715 us; speedup vs baseline: 1.0731x; 1.0731x over previous
//
#include <hip/hip_runtime.h>
#include <math.h>

// Problem constants (from reference): T=512, E=64, H=2*E=128.
#define TT 512
#define EE 64
#define HH 128
#define UNROLL 4

typedef float v4f __attribute__((ext_vector_type(4)));

// Kernel 1: rows[d][h] = (gelu_exact(pos[d] @ W1 + b1) @ W2 + b2)[h]
// One block per distance d (512 blocks), 128 threads (one per output column h).
__global__ void rows_kernel(const float* __restrict__ pos,
                            const float* __restrict__ W1,
                            const float* __restrict__ b1,
                            const float* __restrict__ W2,
                            const float* __restrict__ b2,
                            float* __restrict__ rows) {
    const int d = blockIdx.x;
    const int t = threadIdx.x;   // 0..127

    __shared__ float p[EE];   // pos_table row d
    __shared__ float h[HH];   // hidden activations

    if (t < EE) p[t] = pos[d * EE + t];
    __syncthreads();

    // h[t] = gelu(pos[d] . W1[:,t] + b1[t]), exact gelu (erf form)
    float acc = b1[t];
#pragma unroll
    for (int e = 0; e < EE; ++e) acc += p[e] * W1[e * HH + t];
    h[t] = 0.5f * acc * (1.0f + erff(acc * 0.7071067811865475f));
    __syncthreads();

    // rows[d][t] = h . W2[:,t] + b2[t]
    float acc2 = b2[t];
#pragma unroll
    for (int k = 0; k < HH; ++k) acc2 += h[k] * W2[k * HH + t];
    rows[d * HH + t] = acc2;
}

// Kernel 2: out[b][i][j][:] = rows[max(i-j,0)][:]
// Exact-cover grid (total4 = b*2^23, always divisible by 256*UNROLL=1024):
// no bounds guard, no exec-mask overhead. UNROLL=4 block-local chunks give
// 4 independent load->store pairs per thread (MLP) at low register pressure.
// Every store instruction is wave-contiguous (64 lanes x 16 B = 1 KB).
// Reads hit the 256 KB rows table in L2.
__global__ __launch_bounds__(256)
void scatter_kernel(const v4f* __restrict__ rows4,
                    v4f* __restrict__ out4) {
    const int base = blockIdx.x * (256 * UNROLL) + threadIdx.x;

    v4f v[UNROLL];
#pragma unroll
    for (int k = 0; k < UNROLL; ++k) {
        const int idx = base + k * 256;
        const int q = idx & 31;                 // float4 within row (HH/4=32)
        const int r = idx >> 5;                 // flat (b,i,j)
        const int j = r & (TT - 1);
        const int i = (r >> 9) & (TT - 1);
        const int d = (i >= j) ? (i - j) : 0;   // tril(i-j)
        v[k] = rows4[d * (HH / 4) + q];         // L2-hot (256 KB table)
    }
#pragma unroll
    for (int k = 0; k < UNROLL; ++k)
        out4[base + k * 256] = v[k];
}

extern "C" void kernel_launch(void* const* d_in, const int* in_sizes, int n_in,
                              void* d_out, int out_size, void* d_ws, size_t ws_size,
                              hipStream_t stream) {
    // setup_inputs order: b(int scalar), pos_table, W1, b1, W2, b2 — all fp32
    const float* pos = (const float*)d_in[1];
    const float* W1  = (const float*)d_in[2];
    const float* b1  = (const float*)d_in[3];
    const float* W2  = (const float*)d_in[4];
    const float* b2  = (const float*)d_in[5];
    float* out  = (float*)d_out;
    float* rows = (float*)d_ws;              // TT*HH*4 = 256 KB scratch

    rows_kernel<<<TT, HH, 0, stream>>>(pos, W1, b1, W2, b2, rows);

    const int total4 = out_size / 4;         // b * 2^23, divisible by 1024
    const int grid   = total4 / (256 * UNROLL);
    scatter_kernel<<<grid, 256, 0, stream>>>((const v4f*)rows, (v4f*)out);
}